// Round 12
// baseline (1010.736 us; speedup 1.0000x reference)
//
#include <hip/hip_runtime.h>
#include <hip/hip_bf16.h>

#define N_NODES 10000
#define IN_DIM 256
#define HID 512      // HEADS*HIDDEN
#define HEADS 8
#define OUT_DIM 256
#define NEG 0.2f
#define CAP 128      // bucket capacity per node (actual max deg ~57 incl self-loop)
#define ZB 40        // zero blocks: ceil(10000/256)
#define TB 64        // transpose blocks: 32 (W1) + 32 (W2)
#define GRID 1024    // == 256 CU * 4 blocks/CU guaranteed by __launch_bounds__(256,4)
#define GB1 628      // (HID/128) * ceil(N_NODES/64) = 4*157
#define GB2 314      // (OUT_DIM/128) * 157 = 2*157

typedef __hip_bfloat16 bf16;
typedef __attribute__((ext_vector_type(8))) short short8;
typedef __attribute__((ext_vector_type(4))) float f32x4;

__device__ __forceinline__ float ldm(const void* p, long i, int mode){
  if(mode) return ((const float*)p)[i];
  return __bfloat162float(((const bf16*)p)[i]);
}
__device__ __forceinline__ unsigned short f2bf(float f){
  bf16 b = __float2bfloat16(f);
  return *(unsigned short*)&b;
}
__device__ __forceinline__ float bflo(unsigned int u){ return __uint_as_float(u<<16); }
__device__ __forceinline__ float bfhi(unsigned int u){ return __uint_as_float(u&0xffff0000u); }

// Shared-memory union: one 28KB block reused across phases.
union SMem {
  struct { short As[64*72]; short Bs[128*72]; float led[64][2]; float ler[64][2]; } g;
  struct { unsigned short tl[64*72]; int sbad; } tp;
  struct { int sbad; } sn;
  struct { int sidx[2][CAP]; float swl[2][CAP*8]; float pws[2][2][8]; float sinv[2][8]; float pacc[2][64][8]; } a1;
  struct { int sidx[4][CAP]; float wl[4][CAP]; } a2;
};

// Software grid barrier (plain launch, co-residency guaranteed by launch_bounds
// arithmetic: 1024 blocks = 256 CU x 4 blocks/CU). Device-scope atomics (m20)
// + __threadfence release/acquire for cross-XCD visibility (G16). Each barrier
// index used exactly once per kernel invocation; counters zeroed by host memset.
__device__ __forceinline__ void gridbar(int* bar, int idx){
  __threadfence();                    // release: my writes visible device-wide
  __syncthreads();                    // whole block's fences done
  if(threadIdx.x==0){
    atomicAdd(&bar[idx], 1);
    while(atomicAdd(&bar[idx], 0) < GRID) __builtin_amdgcn_s_sleep(16);
  }
  __syncthreads();
  __threadfence();                    // acquire: drop stale cache lines
}

// ---- device phase bodies (verified R7 kernels re-expressed) ----

__device__ void transpose_tile(SMem* sm, int bb0, int t, const void* W1, const void* W2,
                               unsigned short* wt1, unsigned short* wt2){
  // self-sniff mode from first 512 elems of W1
  const unsigned short* w1raw = (const unsigned short*)W1;
  if(t==0) sm->tp.sbad=0;
  __syncthreads();
  int bad=0;
  for(int i=t;i<512;i+=256){
    unsigned int u = ((unsigned int)w1raw[i])<<16;
    float f = __uint_as_float(u);
    if(!(f==f) || fabsf(f) > 100.0f) bad++;
  }
  #pragma unroll
  for(int o=32;o>0;o>>=1) bad += __shfl_down(bad,o);
  if((t&63)==0) atomicAdd(&sm->tp.sbad, bad);
  __syncthreads();
  int md = sm->tp.sbad>10;
  int isW2 = (bb0>=32);
  int bb = isW2 ? bb0-32 : bb0;
  const void* W = isW2 ? W2 : W1;
  unsigned short* wt = isW2 ? wt2 : wt1;
  int K = isW2 ? HID : IN_DIM;      // rows of W (contraction dim)
  int N = isW2 ? OUT_DIM : HID;     // cols of W
  int sh = isW2 ? 2 : 3;            // log2(ntiles in N)
  int kt = bb >> sh, nt = bb & ((1<<sh)-1);
  int r = t>>2, c0 = (t&3)<<4;      // each thread: 16 elems of one row
  long srow = (long)(kt*64 + r)*N + nt*64 + c0;
  unsigned short v[16] __attribute__((aligned(16)));
  if(md){
    const float* Wf = (const float*)W;
    #pragma unroll
    for(int j=0;j<16;j+=4){
      float4 xv = *(const float4*)(Wf + srow + j);
      v[j]=f2bf(xv.x); v[j+1]=f2bf(xv.y); v[j+2]=f2bf(xv.z); v[j+3]=f2bf(xv.w);
    }
  } else {
    const unsigned short* Wb = (const unsigned short*)W;
    *(short8*)&v[0] = *(const short8*)(Wb+srow);
    *(short8*)&v[8] = *(const short8*)(Wb+srow+8);
  }
  #pragma unroll
  for(int j=0;j<16;j++) sm->tp.tl[(c0+j)*72 + r] = v[j];   // transposed LDS write
  __syncthreads();
  int nn = t>>2, k0 = (t&3)<<4;
  short8 o0 = *(short8*)&sm->tp.tl[nn*72+k0];              // contiguous LDS read
  short8 o1 = *(short8*)&sm->tp.tl[nn*72+k0+8];
  long drow = (long)(nt*64+nn)*K + kt*64 + k0;
  *(short8*)(wt+drow)   = o0;                              // coalesced 16B stores
  *(short8*)(wt+drow+8) = o1;
}

// BM=64 x BN=128 gemm tile with fused attention-dot epilogue (R7 body).
__device__ void gemm_tile(SMem* sm, const void* A, const unsigned short* Bt,
                          unsigned short* C, int M, int N, int K, int am, int md,
                          const void* al, const void* ar, float* el, float* er,
                          int dmode, int blk, int nbx, int t){
  short* As = sm->g.As;
  short* Bs = sm->g.Bs;
  int lane = t & 63, wave = t >> 6;
  int l15 = lane & 15, quad = lane >> 4;
  int wm = (wave>>1)*32, wn = (wave&1)*64;
  int bx = blk % nbx, by = blk / nbx;
  int mbase = by*64, nbase = bx*128;

  f32x4 acc[2][4];
  #pragma unroll
  for(int i=0;i<2;i++)
    #pragma unroll
    for(int j=0;j<4;j++) acc[i][j] = (f32x4){0.f,0.f,0.f,0.f};

  int arw = t>>2, akk = (t&3)*16;
  int brw = t>>1, bkk = (t&1)*32;
  long arow = (long)(mbase+arw)*K, brow = (long)(nbase+brw)*K;
  bool av = (mbase+arw) < M;
  const unsigned short* Ab = (const unsigned short*)A;
  const float* Af = (const float*)A;

  short8 a0,a1,b0,b1,b2,b3, na0,na1,nb0,nb1,nb2,nb3;
  a0=a1 = (short8){0,0,0,0,0,0,0,0};
  na0=na1 = (short8){0,0,0,0,0,0,0,0};

  {
    long ao = arow + akk;
    if(am){
      if(av){
        float4 x0 = *(const float4*)(Af+ao),   x1 = *(const float4*)(Af+ao+4);
        float4 x2 = *(const float4*)(Af+ao+8), x3 = *(const float4*)(Af+ao+12);
        a0[0]=f2bf(x0.x);a0[1]=f2bf(x0.y);a0[2]=f2bf(x0.z);a0[3]=f2bf(x0.w);
        a0[4]=f2bf(x1.x);a0[5]=f2bf(x1.y);a0[6]=f2bf(x1.z);a0[7]=f2bf(x1.w);
        a1[0]=f2bf(x2.x);a1[1]=f2bf(x2.y);a1[2]=f2bf(x2.z);a1[3]=f2bf(x2.w);
        a1[4]=f2bf(x3.x);a1[5]=f2bf(x3.y);a1[6]=f2bf(x3.z);a1[7]=f2bf(x3.w);
      }
    } else if(av){
      a0 = *(const short8*)(Ab+ao); a1 = *(const short8*)(Ab+ao+8);
    }
    long bo = brow + bkk;
    b0 = *(const short8*)(Bt+bo);    b1 = *(const short8*)(Bt+bo+8);
    b2 = *(const short8*)(Bt+bo+16); b3 = *(const short8*)(Bt+bo+24);
  }

  for(int k0=0;k0<K;k0+=64){
    if(k0+64 < K){
      long ao = arow + k0 + 64 + akk;
      if(am){
        if(av){
          float4 x0 = *(const float4*)(Af+ao),   x1 = *(const float4*)(Af+ao+4);
          float4 x2 = *(const float4*)(Af+ao+8), x3 = *(const float4*)(Af+ao+12);
          na0[0]=f2bf(x0.x);na0[1]=f2bf(x0.y);na0[2]=f2bf(x0.z);na0[3]=f2bf(x0.w);
          na0[4]=f2bf(x1.x);na0[5]=f2bf(x1.y);na0[6]=f2bf(x1.z);na0[7]=f2bf(x1.w);
          na1[0]=f2bf(x2.x);na1[1]=f2bf(x2.y);na1[2]=f2bf(x2.z);na1[3]=f2bf(x2.w);
          na1[4]=f2bf(x3.x);na1[5]=f2bf(x3.y);na1[6]=f2bf(x3.z);na1[7]=f2bf(x3.w);
        }
      } else if(av){
        na0 = *(const short8*)(Ab+ao); na1 = *(const short8*)(Ab+ao+8);
      }
      long bo = brow + k0 + 64 + bkk;
      nb0 = *(const short8*)(Bt+bo);    nb1 = *(const short8*)(Bt+bo+8);
      nb2 = *(const short8*)(Bt+bo+16); nb3 = *(const short8*)(Bt+bo+24);
    }
    __syncthreads();
    *(short8*)(As + arw*72 + akk)   = a0;
    *(short8*)(As + arw*72 + akk+8) = a1;
    *(short8*)(Bs + brw*72 + bkk)    = b0;
    *(short8*)(Bs + brw*72 + bkk+8)  = b1;
    *(short8*)(Bs + brw*72 + bkk+16) = b2;
    *(short8*)(Bs + brw*72 + bkk+24) = b3;
    __syncthreads();
    #pragma unroll
    for(int ks=0;ks<2;ks++){
      short8 af[2], bfr[4];
      #pragma unroll
      for(int mi=0;mi<2;mi++) af[mi]  = *(short8*)(As + (wm + mi*16 + l15)*72 + ks*32 + quad*8);
      #pragma unroll
      for(int ni=0;ni<4;ni++) bfr[ni] = *(short8*)(Bs + (wn + ni*16 + l15)*72 + ks*32 + quad*8);
      #pragma unroll
      for(int mi=0;mi<2;mi++)
        #pragma unroll
        for(int ni=0;ni<4;ni++)
          acc[mi][ni] = __builtin_amdgcn_mfma_f32_16x16x32_bf16(af[mi], bfr[ni], acc[mi][ni], 0,0,0);
    }
    a0=na0; a1=na1; b0=nb0; b1=nb1; b2=nb2; b3=nb3;
  }

  #pragma unroll
  for(int mi=0;mi<2;mi++){
    #pragma unroll
    for(int ni=0;ni<4;ni++){
      int grow0 = mbase + wm + mi*16 + quad*4;
      int gcol  = nbase + wn + ni*16 + l15;
      #pragma unroll
      for(int r=0;r<4;r++){
        int grow = grow0 + r;
        if(grow < M) C[(long)grow*N + gcol] = f2bf(acc[mi][ni][r]);
      }
    }
  }

  float avv[4], rvv[4];
  #pragma unroll
  for(int ni=0;ni<4;ni++){
    int gc = nbase + wn + ni*16 + l15;
    avv[ni] = ldm(al, gc, md);
    rvv[ni] = ldm(ar, gc, md);
  }
  int hh = wn>>6;
  __syncthreads();
  if(t<128){ sm->g.led[t&63][t>>6]=0.f; sm->g.ler[t&63][t>>6]=0.f; }
  __syncthreads();
  #pragma unroll
  for(int mi=0;mi<2;mi++){
    #pragma unroll
    for(int r=0;r<4;r++){
      float pl = acc[mi][0][r]*avv[0] + acc[mi][1][r]*avv[1]
               + acc[mi][2][r]*avv[2] + acc[mi][3][r]*avv[3];
      float pr = acc[mi][0][r]*rvv[0] + acc[mi][1][r]*rvv[1]
               + acc[mi][2][r]*rvv[2] + acc[mi][3][r]*rvv[3];
      #pragma unroll
      for(int o=1;o<16;o<<=1){ pl += __shfl_xor(pl,o); pr += __shfl_xor(pr,o); }
      if(l15==0){
        int lr = wm + mi*16 + quad*4 + r;
        atomicAdd(&sm->g.led[lr][hh], pl);
        atomicAdd(&sm->g.ler[lr][hh], pr);
      }
    }
  }
  __syncthreads();
  if(dmode==1){
    if(t<128){
      int grow = mbase + (t&63);
      int h2 = t>>6;
      if(grow < M){
        el[(long)grow*HEADS + 2*bx + h2] = sm->g.led[t&63][h2];
        er[(long)grow*HEADS + 2*bx + h2] = sm->g.ler[t&63][h2];
      }
    }
  } else {
    if(t<64){
      int grow = mbase + t;
      if(grow < M){
        atomicAdd(&el[grow], sm->g.led[t][0]+sm->g.led[t][1]);
        atomicAdd(&er[grow], sm->g.ler[t][0]+sm->g.ler[t][1]);
      }
    }
  }
}

// Layer-1 agg for one node, executed by a 128-thread sub-block g (R7 agg1_k body).
__device__ void agg1_node(SMem* sm, int g, int t, int n, const unsigned short* fb,
                          const float* el, const float* er, const int* cnt,
                          const int* bucket, unsigned short* x){
  long off = (long)n*CAP;
  int deg = cnt[n]; if(deg>CAP) deg=CAP;
  int* sidx = sm->a1.sidx[g];
  float* swl = sm->a1.swl[g];
  for(int i=t;i<deg;i+=128) sidx[i]=bucket[off+i];
  __syncthreads();
  const float* erp = er + (long)n*HEADS;
  float4 era = *(const float4*)erp, erb = *(const float4*)(erp+4);
  float err8[8] = {era.x,era.y,era.z,era.w,erb.x,erb.y,erb.z,erb.w};
  float pw[8];
  #pragma unroll
  for(int j=0;j<8;j++) pw[j]=0.f;
  for(int i=t;i<deg;i+=128){
    int s = sidx[i];
    const float* ep = el + (long)s*HEADS;
    float4 ea = *(const float4*)ep, eb = *(const float4*)(ep+4);
    float ev[8] = {ea.x,ea.y,ea.z,ea.w,eb.x,eb.y,eb.z,eb.w};
    float wv[8];
    #pragma unroll
    for(int j=0;j<8;j++){
      float e = ev[j] + err8[j];
      e = e>0.f ? e : NEG*e;
      float w = __expf(e);
      wv[j]=w; pw[j]+=w;
    }
    *(float4*)&swl[i*8]   = make_float4(wv[0],wv[1],wv[2],wv[3]);
    *(float4*)&swl[i*8+4] = make_float4(wv[4],wv[5],wv[6],wv[7]);
  }
  #pragma unroll
  for(int o=32;o>0;o>>=1)
    #pragma unroll
    for(int j=0;j<8;j++) pw[j]+=__shfl_xor(pw[j],o);
  int wv_ = t>>6, l = t&63;
  if(l==0){
    #pragma unroll
    for(int j=0;j<8;j++) sm->a1.pws[g][wv_][j]=pw[j];
  }
  __syncthreads();
  if(t<8){
    float s2 = sm->a1.pws[g][0][t]+sm->a1.pws[g][1][t];
    sm->a1.sinv[g][t] = s2>0.f ? 1.f/s2 : 0.f;
  }
  __syncthreads();
  int h = l>>3;
  int c0 = 8*l;
  float a0=0.f,a1=0.f,a2=0.f,a3=0.f,a4=0.f,a5=0.f,a6=0.f,a7=0.f;
  #pragma unroll 4
  for(int i=wv_; i<deg; i+=2){
    int s = sidx[i];
    float w = swl[i*8+h];
    uint4 u = *(const uint4*)(fb + (long)s*HID + c0);
    a0 += w*bflo(u.x); a1 += w*bfhi(u.x);
    a2 += w*bflo(u.y); a3 += w*bfhi(u.y);
    a4 += w*bflo(u.z); a5 += w*bfhi(u.z);
    a6 += w*bflo(u.w); a7 += w*bfhi(u.w);
  }
  if(wv_==1){
    *(float4*)&sm->a1.pacc[g][l][0] = make_float4(a0,a1,a2,a3);
    *(float4*)&sm->a1.pacc[g][l][4] = make_float4(a4,a5,a6,a7);
  }
  __syncthreads();
  if(wv_==0){
    float4 q0 = *(float4*)&sm->a1.pacc[g][l][0], q1 = *(float4*)&sm->a1.pacc[g][l][4];
    a0+=q0.x; a1+=q0.y; a2+=q0.z; a3+=q0.w;
    a4+=q1.x; a5+=q1.y; a6+=q1.z; a7+=q1.w;
    float inv = sm->a1.sinv[g][h];
    a0*=inv; a1*=inv; a2*=inv; a3*=inv; a4*=inv; a5*=inv; a6*=inv; a7*=inv;
    a0 = a0>0.f ? a0 : __expf(a0)-1.f;   // ELU
    a1 = a1>0.f ? a1 : __expf(a1)-1.f;
    a2 = a2>0.f ? a2 : __expf(a2)-1.f;
    a3 = a3>0.f ? a3 : __expf(a3)-1.f;
    a4 = a4>0.f ? a4 : __expf(a4)-1.f;
    a5 = a5>0.f ? a5 : __expf(a5)-1.f;
    a6 = a6>0.f ? a6 : __expf(a6)-1.f;
    a7 = a7>0.f ? a7 : __expf(a7)-1.f;
    uint4 o4;
    o4.x = (unsigned int)f2bf(a0) | ((unsigned int)f2bf(a1)<<16);
    o4.y = (unsigned int)f2bf(a2) | ((unsigned int)f2bf(a3)<<16);
    o4.z = (unsigned int)f2bf(a4) | ((unsigned int)f2bf(a5)<<16);
    o4.w = (unsigned int)f2bf(a6) | ((unsigned int)f2bf(a7)<<16);
    *(uint4*)(x + (long)n*HID + c0) = o4;
  }
}

// Layer-2 agg for one node, executed by a 64-thread sub-block g (R7 agg2_k body).
__device__ void agg2_node(SMem* sm, int g, int t, int n, const unsigned short* fb,
                          const float* el, const float* er, const int* cnt,
                          const int* bucket, void* out, int md){
  long off = (long)n*CAP;
  int deg = cnt[n]; if(deg>CAP) deg=CAP;
  int* sidx = sm->a2.sidx[g];
  float* wl = sm->a2.wl[g];
  for(int i=t;i<deg;i+=64) sidx[i]=bucket[off+i];
  __syncthreads();
  float ern = er[n];
  float pw = 0.f;
  for(int i=t;i<deg;i+=64){
    int s = sidx[i];
    float e = el[s]+ern; e = e>0.f ? e : NEG*e;
    float w = __expf(e);
    wl[i]=w;
    pw += w;
  }
  #pragma unroll
  for(int o=32;o>0;o>>=1) pw += __shfl_xor(pw,o);
  float inv = pw>0.f ? 1.f/pw : 0.f;
  __syncthreads();
  int half = t>>5, l = t&31;
  int c0 = 8*l;
  float a0=0.f,a1=0.f,a2=0.f,a3=0.f,a4=0.f,a5=0.f,a6=0.f,a7=0.f;
  #pragma unroll 4
  for(int i=half; i<deg; i+=2){
    int s = sidx[i];
    float w = wl[i];
    uint4 u = *(const uint4*)(fb + (long)s*OUT_DIM + c0);
    a0 += w*bflo(u.x); a1 += w*bfhi(u.x);
    a2 += w*bflo(u.y); a3 += w*bfhi(u.y);
    a4 += w*bflo(u.z); a5 += w*bfhi(u.z);
    a6 += w*bflo(u.w); a7 += w*bfhi(u.w);
  }
  a0 += __shfl_xor(a0,32); a1 += __shfl_xor(a1,32);
  a2 += __shfl_xor(a2,32); a3 += __shfl_xor(a3,32);
  a4 += __shfl_xor(a4,32); a5 += __shfl_xor(a5,32);
  a6 += __shfl_xor(a6,32); a7 += __shfl_xor(a7,32);
  if(half==0){
    a0*=inv; a1*=inv; a2*=inv; a3*=inv; a4*=inv; a5*=inv; a6*=inv; a7*=inv;
    long oi = (long)n*OUT_DIM + c0;
    if(md){
      float* of = (float*)out;
      *(float4*)(of+oi)   = make_float4(a0,a1,a2,a3);
      *(float4*)(of+oi+4) = make_float4(a4,a5,a6,a7);
    } else {
      unsigned short* ob = (unsigned short*)out;
      uint4 o4;
      o4.x = (unsigned int)f2bf(a0) | ((unsigned int)f2bf(a1)<<16);
      o4.y = (unsigned int)f2bf(a2) | ((unsigned int)f2bf(a3)<<16);
      o4.z = (unsigned int)f2bf(a4) | ((unsigned int)f2bf(a5)<<16);
      o4.w = (unsigned int)f2bf(a6) | ((unsigned int)f2bf(a7)<<16);
      *(uint4*)(ob+oi) = o4;
    }
  }
}

// ---- single persistent kernel: 5 phases, 4 software grid barriers ----
__global__ __launch_bounds__(256,4) void fused_k(
    const void* h_in, const void* W1, const void* al1, const void* ar1,
    const void* W2, const void* al2, const void* ar2,
    const int* src, const int* dst, int E,
    unsigned short* f1b, unsigned short* f2b, unsigned short* xbuf,
    unsigned short* wt1, unsigned short* wt2,
    float* el1, float* er1, float* el2, float* er2,
    int* cnt, int* bucket, int* modep, int* bar, void* out){
  int blk = blockIdx.x, t = threadIdx.x;
  __shared__ SMem sm;

  // phase 0: transpose (blocks 0..TB-1), global sniff (TB), zero (TB+1..TB+ZB)
  if(blk < TB){
    transpose_tile(&sm, blk, t, W1, W2, wt1, wt2);
  } else if(blk == TB){
    const unsigned short* w1raw = (const unsigned short*)W1;
    if(t==0) sm.sn.sbad=0;
    __syncthreads();
    int bad=0;
    for(int i=t;i<512;i+=256){
      unsigned int u = ((unsigned int)w1raw[i])<<16;
      float f = __uint_as_float(u);
      if(!(f==f) || fabsf(f) > 100.0f) bad++;
    }
    #pragma unroll
    for(int o=32;o>0;o>>=1) bad += __shfl_down(bad,o);
    if((t&63)==0) atomicAdd(&sm.sn.sbad, bad);
    __syncthreads();
    if(t==0) *modep = (sm.sn.sbad>10) ? 1 : 0;
  } else if(blk < TB+1+ZB){
    int i = (blk-TB-1)*256 + t;
    if(i<N_NODES){ cnt[i]=0; el2[i]=0.f; er2[i]=0.f; }
  }
  gridbar(bar, 0);
  int md = *modep;

  // phase B: gemm1 tiles on blocks [0,GB1); edge-bucket scatter on the rest
  if(blk < GB1){
    gemm_tile(&sm, h_in, wt1, f1b, N_NODES, HID, IN_DIM, md, md,
              al1, ar1, el1, er1, 1, blk, HID/128, t);
  } else {
    for(long e=(long)(blk-GB1)*256 + t; e<E; e+=(long)(GRID-GB1)*256){
      int d = dst[e];
      int pos = atomicAdd(&cnt[d], 1);
      if(pos < CAP) bucket[(long)d*CAP + pos] = src[e];
    }
  }
  gridbar(bar, 1);

  // phase C: layer-1 aggregation + ELU, 2 nodes per block per iteration
  {
    int g = t>>7, t128 = t&127;
    for(int i=blk; i<N_NODES/2; i+=GRID){
      int n = i*2 + g;
      agg1_node(&sm, g, t128, n, f1b, el1, er1, cnt, bucket, xbuf);
      __syncthreads();
    }
  }
  gridbar(bar, 2);

  // phase D: gemm2 tiles on blocks [0,GB2)
  if(blk < GB2){
    gemm_tile(&sm, xbuf, wt2, f2b, N_NODES, OUT_DIM, HID, 0, md,
              al2, ar2, el2, er2, 2, blk, OUT_DIM/128, t);
  }
  gridbar(bar, 3);

  // phase E: layer-2 aggregation, 4 nodes per block per iteration
  {
    int g = t>>6, t64 = t&63;
    for(int i=blk; i<N_NODES/4; i+=GRID){
      int n = i*4 + g;
      agg2_node(&sm, g, t64, n, f2b, el2, er2, cnt, bucket, out, md);
      __syncthreads();
    }
  }
}

extern "C" void kernel_launch(void* const* d_in, const int* in_sizes, int n_in,
                              void* d_out, int out_size, void* d_ws, size_t ws_size,
                              hipStream_t stream){
  (void)n_in; (void)out_size; (void)ws_size;
  const void* h_in = d_in[0];
  const void* W1   = d_in[1];
  const void* al1  = d_in[2];
  const void* ar1  = d_in[3];
  const void* W2   = d_in[4];
  const void* al2  = d_in[5];
  const void* ar2  = d_in[6];
  const int* src = (const int*)d_in[7];
  const int* dst = (const int*)d_in[8];
  int E = in_sizes[7];

  char* ws = (char*)d_ws;
  size_t o = 0;
  auto alloc = [&](size_t b){ size_t c=o; o += (b+255)&~(size_t)255; return c; };
  unsigned short* f1b  = (unsigned short*)(ws + alloc((size_t)N_NODES*HID*2));
  unsigned short* f2b  = (unsigned short*)(ws + alloc((size_t)N_NODES*OUT_DIM*2));
  unsigned short* xbuf = (unsigned short*)(ws + alloc((size_t)N_NODES*HID*2));
  unsigned short* wt1  = (unsigned short*)(ws + alloc((size_t)IN_DIM*HID*2));
  unsigned short* wt2  = (unsigned short*)(ws + alloc((size_t)HID*OUT_DIM*2));
  float* el1   = (float*)(ws + alloc((size_t)N_NODES*HEADS*4));
  float* er1   = (float*)(ws + alloc((size_t)N_NODES*HEADS*4));
  float* el2   = (float*)(ws + alloc((size_t)N_NODES*4));
  float* er2   = (float*)(ws + alloc((size_t)N_NODES*4));
  int* cnt     = (int*)(ws + alloc((size_t)N_NODES*4));
  int* bucket  = (int*)(ws + alloc((size_t)N_NODES*CAP*4));
  int* modep   = (int*)(ws + alloc(256));
  int* bar     = (int*)(ws + alloc(256));

  // zero the 4 barrier counters (capturable async memset, per-invocation)
  hipMemsetAsync(bar, 0, 64, stream);

  fused_k<<<GRID,256,0,stream>>>(
      h_in, W1, al1, ar1, W2, al2, ar2, src, dst, E,
      f1b, f2b, xbuf, wt1, wt2, el1, er1, el2, er2,
      cnt, bucket, modep, bar, d_out);
}

// Round 16
// 989.870 us; speedup vs baseline: 1.0211x; 1.0211x over previous
//
#include <hip/hip_runtime.h>
#include <hip/hip_bf16.h>

#define N_NODES 10000
#define IN_DIM 256
#define HID 512      // HEADS*HIDDEN
#define HEADS 8
#define OUT_DIM 256
#define NEG 0.2f
#define CAP 128      // bucket capacity per node (actual max deg ~57 incl self-loop)
#define ZB 40        // zero blocks: ceil(10000/256)
#define TB 64        // transpose blocks: 32 (W1) + 32 (W2)
#define GRID 1024    // == 256 CU * 4 blocks/CU guaranteed by __launch_bounds__(256,4)
#define GB1 628      // (HID/128) * ceil(N_NODES/64) = 4*157
#define GB2 314      // (OUT_DIM/128) * 157 = 2*157

typedef __hip_bfloat16 bf16;
typedef __attribute__((ext_vector_type(8))) short short8;
typedef __attribute__((ext_vector_type(4))) float f32x4;

__device__ __forceinline__ float ldm(const void* p, long i, int mode){
  if(mode) return ((const float*)p)[i];
  return __bfloat162float(((const bf16*)p)[i]);
}
__device__ __forceinline__ unsigned short f2bf(float f){
  bf16 b = __float2bfloat16(f);
  return *(unsigned short*)&b;
}
__device__ __forceinline__ float bflo(unsigned int u){ return __uint_as_float(u<<16); }
__device__ __forceinline__ float bfhi(unsigned int u){ return __uint_as_float(u&0xffff0000u); }

// Shared-memory union: one 28KB block reused across phases.
union SMem {
  struct { short As[64*72]; short Bs[128*72]; float led[64][2]; float ler[64][2]; } g;
  struct { unsigned short tl[64*72]; int sbad; } tp;
  struct { int sbad; } sn;
  struct { int sidx[2][CAP]; float swl[2][CAP*8]; float pws[2][2][8]; float sinv[2][8]; float pacc[2][64][8]; } a1;
  struct { int sidx[4][CAP]; float wl[4][CAP]; } a2;
};

// Two-phase sense barrier, contention-minimized (R12 post-mortem: RMW-spin
// polls caused 179MB of line fetches + atomic serialization = 800us).
// Layout per barrier idx: bar[idx*64] = arrival counter (own 128B line),
// bar[idx*64+32] = release flag (separate 128B line). Arrival: ONE atomicAdd
// per block. Wait: relaxed scoped atomic LOAD (no RMW, no line ownership)
// + s_sleep(127) (~3.4us) backoff -> ~1e3 polls/barrier instead of 1e6.
// Co-residency: 1024 blocks = 256 CU x 4 blocks/CU via __launch_bounds__(256,4),
// LDS 28KB (5/CU cap). Counters zeroed per-invocation by capturable memset.
__device__ __forceinline__ void gridbar(int* bar, int idx){
  __threadfence();                    // release: my writes visible device-wide
  __syncthreads();                    // whole block's fences done
  if(threadIdx.x==0){
    int* cntp  = bar + idx*64;
    int* flagp = bar + idx*64 + 32;
    int arrived = atomicAdd(cntp, 1) + 1;
    if(arrived == GRID){
      __hip_atomic_store(flagp, 1, __ATOMIC_RELEASE, __HIP_MEMORY_SCOPE_AGENT);
    } else {
      while(__hip_atomic_load(flagp, __ATOMIC_ACQUIRE, __HIP_MEMORY_SCOPE_AGENT) == 0)
        __builtin_amdgcn_s_sleep(127);
    }
  }
  __syncthreads();
  __threadfence();                    // acquire: drop stale cache lines
}

// ---- device phase bodies (verified R7 kernels re-expressed) ----

__device__ void transpose_tile(SMem* sm, int bb0, int t, const void* W1, const void* W2,
                               unsigned short* wt1, unsigned short* wt2){
  // self-sniff mode from first 512 elems of W1
  const unsigned short* w1raw = (const unsigned short*)W1;
  if(t==0) sm->tp.sbad=0;
  __syncthreads();
  int bad=0;
  for(int i=t;i<512;i+=256){
    unsigned int u = ((unsigned int)w1raw[i])<<16;
    float f = __uint_as_float(u);
    if(!(f==f) || fabsf(f) > 100.0f) bad++;
  }
  #pragma unroll
  for(int o=32;o>0;o>>=1) bad += __shfl_down(bad,o);
  if((t&63)==0) atomicAdd(&sm->tp.sbad, bad);
  __syncthreads();
  int md = sm->tp.sbad>10;
  int isW2 = (bb0>=32);
  int bb = isW2 ? bb0-32 : bb0;
  const void* W = isW2 ? W2 : W1;
  unsigned short* wt = isW2 ? wt2 : wt1;
  int K = isW2 ? HID : IN_DIM;      // rows of W (contraction dim)
  int N = isW2 ? OUT_DIM : HID;     // cols of W
  int sh = isW2 ? 2 : 3;            // log2(ntiles in N)
  int kt = bb >> sh, nt = bb & ((1<<sh)-1);
  int r = t>>2, c0 = (t&3)<<4;      // each thread: 16 elems of one row
  long srow = (long)(kt*64 + r)*N + nt*64 + c0;
  unsigned short v[16] __attribute__((aligned(16)));
  if(md){
    const float* Wf = (const float*)W;
    #pragma unroll
    for(int j=0;j<16;j+=4){
      float4 xv = *(const float4*)(Wf + srow + j);
      v[j]=f2bf(xv.x); v[j+1]=f2bf(xv.y); v[j+2]=f2bf(xv.z); v[j+3]=f2bf(xv.w);
    }
  } else {
    const unsigned short* Wb = (const unsigned short*)W;
    *(short8*)&v[0] = *(const short8*)(Wb+srow);
    *(short8*)&v[8] = *(const short8*)(Wb+srow+8);
  }
  #pragma unroll
  for(int j=0;j<16;j++) sm->tp.tl[(c0+j)*72 + r] = v[j];   // transposed LDS write
  __syncthreads();
  int nn = t>>2, k0 = (t&3)<<4;
  short8 o0 = *(short8*)&sm->tp.tl[nn*72+k0];              // contiguous LDS read
  short8 o1 = *(short8*)&sm->tp.tl[nn*72+k0+8];
  long drow = (long)(nt*64+nn)*K + kt*64 + k0;
  *(short8*)(wt+drow)   = o0;                              // coalesced 16B stores
  *(short8*)(wt+drow+8) = o1;
}

// BM=64 x BN=128 gemm tile with fused attention-dot epilogue (R7 body).
__device__ void gemm_tile(SMem* sm, const void* A, const unsigned short* Bt,
                          unsigned short* C, int M, int N, int K, int am, int md,
                          const void* al, const void* ar, float* el, float* er,
                          int dmode, int blk, int nbx, int t){
  short* As = sm->g.As;
  short* Bs = sm->g.Bs;
  int lane = t & 63, wave = t >> 6;
  int l15 = lane & 15, quad = lane >> 4;
  int wm = (wave>>1)*32, wn = (wave&1)*64;
  int bx = blk % nbx, by = blk / nbx;
  int mbase = by*64, nbase = bx*128;

  f32x4 acc[2][4];
  #pragma unroll
  for(int i=0;i<2;i++)
    #pragma unroll
    for(int j=0;j<4;j++) acc[i][j] = (f32x4){0.f,0.f,0.f,0.f};

  int arw = t>>2, akk = (t&3)*16;
  int brw = t>>1, bkk = (t&1)*32;
  long arow = (long)(mbase+arw)*K, brow = (long)(nbase+brw)*K;
  bool av = (mbase+arw) < M;
  const unsigned short* Ab = (const unsigned short*)A;
  const float* Af = (const float*)A;

  short8 a0,a1,b0,b1,b2,b3, na0,na1,nb0,nb1,nb2,nb3;
  a0=a1 = (short8){0,0,0,0,0,0,0,0};
  na0=na1 = (short8){0,0,0,0,0,0,0,0};

  {
    long ao = arow + akk;
    if(am){
      if(av){
        float4 x0 = *(const float4*)(Af+ao),   x1 = *(const float4*)(Af+ao+4);
        float4 x2 = *(const float4*)(Af+ao+8), x3 = *(const float4*)(Af+ao+12);
        a0[0]=f2bf(x0.x);a0[1]=f2bf(x0.y);a0[2]=f2bf(x0.z);a0[3]=f2bf(x0.w);
        a0[4]=f2bf(x1.x);a0[5]=f2bf(x1.y);a0[6]=f2bf(x1.z);a0[7]=f2bf(x1.w);
        a1[0]=f2bf(x2.x);a1[1]=f2bf(x2.y);a1[2]=f2bf(x2.z);a1[3]=f2bf(x2.w);
        a1[4]=f2bf(x3.x);a1[5]=f2bf(x3.y);a1[6]=f2bf(x3.z);a1[7]=f2bf(x3.w);
      }
    } else if(av){
      a0 = *(const short8*)(Ab+ao); a1 = *(const short8*)(Ab+ao+8);
    }
    long bo = brow + bkk;
    b0 = *(const short8*)(Bt+bo);    b1 = *(const short8*)(Bt+bo+8);
    b2 = *(const short8*)(Bt+bo+16); b3 = *(const short8*)(Bt+bo+24);
  }

  for(int k0=0;k0<K;k0+=64){
    if(k0+64 < K){
      long ao = arow + k0 + 64 + akk;
      if(am){
        if(av){
          float4 x0 = *(const float4*)(Af+ao),   x1 = *(const float4*)(Af+ao+4);
          float4 x2 = *(const float4*)(Af+ao+8), x3 = *(const float4*)(Af+ao+12);
          na0[0]=f2bf(x0.x);na0[1]=f2bf(x0.y);na0[2]=f2bf(x0.z);na0[3]=f2bf(x0.w);
          na0[4]=f2bf(x1.x);na0[5]=f2bf(x1.y);na0[6]=f2bf(x1.z);na0[7]=f2bf(x1.w);
          na1[0]=f2bf(x2.x);na1[1]=f2bf(x2.y);na1[2]=f2bf(x2.z);na1[3]=f2bf(x2.w);
          na1[4]=f2bf(x3.x);na1[5]=f2bf(x3.y);na1[6]=f2bf(x3.z);na1[7]=f2bf(x3.w);
        }
      } else if(av){
        na0 = *(const short8*)(Ab+ao); na1 = *(const short8*)(Ab+ao+8);
      }
      long bo = brow + k0 + 64 + bkk;
      nb0 = *(const short8*)(Bt+bo);    nb1 = *(const short8*)(Bt+bo+8);
      nb2 = *(const short8*)(Bt+bo+16); nb3 = *(const short8*)(Bt+bo+24);
    }
    __syncthreads();
    *(short8*)(As + arw*72 + akk)   = a0;
    *(short8*)(As + arw*72 + akk+8) = a1;
    *(short8*)(Bs + brw*72 + bkk)    = b0;
    *(short8*)(Bs + brw*72 + bkk+8)  = b1;
    *(short8*)(Bs + brw*72 + bkk+16) = b2;
    *(short8*)(Bs + brw*72 + bkk+24) = b3;
    __syncthreads();
    #pragma unroll
    for(int ks=0;ks<2;ks++){
      short8 af[2], bfr[4];
      #pragma unroll
      for(int mi=0;mi<2;mi++) af[mi]  = *(short8*)(As + (wm + mi*16 + l15)*72 + ks*32 + quad*8);
      #pragma unroll
      for(int ni=0;ni<4;ni++) bfr[ni] = *(short8*)(Bs + (wn + ni*16 + l15)*72 + ks*32 + quad*8);
      #pragma unroll
      for(int mi=0;mi<2;mi++)
        #pragma unroll
        for(int ni=0;ni<4;ni++)
          acc[mi][ni] = __builtin_amdgcn_mfma_f32_16x16x32_bf16(af[mi], bfr[ni], acc[mi][ni], 0,0,0);
    }
    a0=na0; a1=na1; b0=nb0; b1=nb1; b2=nb2; b3=nb3;
  }

  #pragma unroll
  for(int mi=0;mi<2;mi++){
    #pragma unroll
    for(int ni=0;ni<4;ni++){
      int grow0 = mbase + wm + mi*16 + quad*4;
      int gcol  = nbase + wn + ni*16 + l15;
      #pragma unroll
      for(int r=0;r<4;r++){
        int grow = grow0 + r;
        if(grow < M) C[(long)grow*N + gcol] = f2bf(acc[mi][ni][r]);
      }
    }
  }

  float avv[4], rvv[4];
  #pragma unroll
  for(int ni=0;ni<4;ni++){
    int gc = nbase + wn + ni*16 + l15;
    avv[ni] = ldm(al, gc, md);
    rvv[ni] = ldm(ar, gc, md);
  }
  int hh = wn>>6;
  __syncthreads();
  if(t<128){ sm->g.led[t&63][t>>6]=0.f; sm->g.ler[t&63][t>>6]=0.f; }
  __syncthreads();
  #pragma unroll
  for(int mi=0;mi<2;mi++){
    #pragma unroll
    for(int r=0;r<4;r++){
      float pl = acc[mi][0][r]*avv[0] + acc[mi][1][r]*avv[1]
               + acc[mi][2][r]*avv[2] + acc[mi][3][r]*avv[3];
      float pr = acc[mi][0][r]*rvv[0] + acc[mi][1][r]*rvv[1]
               + acc[mi][2][r]*rvv[2] + acc[mi][3][r]*rvv[3];
      #pragma unroll
      for(int o=1;o<16;o<<=1){ pl += __shfl_xor(pl,o); pr += __shfl_xor(pr,o); }
      if(l15==0){
        int lr = wm + mi*16 + quad*4 + r;
        atomicAdd(&sm->g.led[lr][hh], pl);
        atomicAdd(&sm->g.ler[lr][hh], pr);
      }
    }
  }
  __syncthreads();
  if(dmode==1){
    if(t<128){
      int grow = mbase + (t&63);
      int h2 = t>>6;
      if(grow < M){
        el[(long)grow*HEADS + 2*bx + h2] = sm->g.led[t&63][h2];
        er[(long)grow*HEADS + 2*bx + h2] = sm->g.ler[t&63][h2];
      }
    }
  } else {
    if(t<64){
      int grow = mbase + t;
      if(grow < M){
        atomicAdd(&el[grow], sm->g.led[t][0]+sm->g.led[t][1]);
        atomicAdd(&er[grow], sm->g.ler[t][0]+sm->g.ler[t][1]);
      }
    }
  }
}

// Layer-1 agg for one node, executed by a 128-thread sub-block g (R7 agg1_k body).
__device__ void agg1_node(SMem* sm, int g, int t, int n, const unsigned short* fb,
                          const float* el, const float* er, const int* cnt,
                          const int* bucket, unsigned short* x){
  long off = (long)n*CAP;
  int deg = cnt[n]; if(deg>CAP) deg=CAP;
  int* sidx = sm->a1.sidx[g];
  float* swl = sm->a1.swl[g];
  for(int i=t;i<deg;i+=128) sidx[i]=bucket[off+i];
  __syncthreads();
  const float* erp = er + (long)n*HEADS;
  float4 era = *(const float4*)erp, erb = *(const float4*)(erp+4);
  float err8[8] = {era.x,era.y,era.z,era.w,erb.x,erb.y,erb.z,erb.w};
  float pw[8];
  #pragma unroll
  for(int j=0;j<8;j++) pw[j]=0.f;
  for(int i=t;i<deg;i+=128){
    int s = sidx[i];
    const float* ep = el + (long)s*HEADS;
    float4 ea = *(const float4*)ep, eb = *(const float4*)(ep+4);
    float ev[8] = {ea.x,ea.y,ea.z,ea.w,eb.x,eb.y,eb.z,eb.w};
    float wv[8];
    #pragma unroll
    for(int j=0;j<8;j++){
      float e = ev[j] + err8[j];
      e = e>0.f ? e : NEG*e;
      float w = __expf(e);
      wv[j]=w; pw[j]+=w;
    }
    *(float4*)&swl[i*8]   = make_float4(wv[0],wv[1],wv[2],wv[3]);
    *(float4*)&swl[i*8+4] = make_float4(wv[4],wv[5],wv[6],wv[7]);
  }
  #pragma unroll
  for(int o=32;o>0;o>>=1)
    #pragma unroll
    for(int j=0;j<8;j++) pw[j]+=__shfl_xor(pw[j],o);
  int wv_ = t>>6, l = t&63;
  if(l==0){
    #pragma unroll
    for(int j=0;j<8;j++) sm->a1.pws[g][wv_][j]=pw[j];
  }
  __syncthreads();
  if(t<8){
    float s2 = sm->a1.pws[g][0][t]+sm->a1.pws[g][1][t];
    sm->a1.sinv[g][t] = s2>0.f ? 1.f/s2 : 0.f;
  }
  __syncthreads();
  int h = l>>3;
  int c0 = 8*l;
  float a0=0.f,a1=0.f,a2=0.f,a3=0.f,a4=0.f,a5=0.f,a6=0.f,a7=0.f;
  #pragma unroll 4
  for(int i=wv_; i<deg; i+=2){
    int s = sidx[i];
    float w = swl[i*8+h];
    uint4 u = *(const uint4*)(fb + (long)s*HID + c0);
    a0 += w*bflo(u.x); a1 += w*bfhi(u.x);
    a2 += w*bflo(u.y); a3 += w*bfhi(u.y);
    a4 += w*bflo(u.z); a5 += w*bfhi(u.z);
    a6 += w*bflo(u.w); a7 += w*bfhi(u.w);
  }
  if(wv_==1){
    *(float4*)&sm->a1.pacc[g][l][0] = make_float4(a0,a1,a2,a3);
    *(float4*)&sm->a1.pacc[g][l][4] = make_float4(a4,a5,a6,a7);
  }
  __syncthreads();
  if(wv_==0){
    float4 q0 = *(float4*)&sm->a1.pacc[g][l][0], q1 = *(float4*)&sm->a1.pacc[g][l][4];
    a0+=q0.x; a1+=q0.y; a2+=q0.z; a3+=q0.w;
    a4+=q1.x; a5+=q1.y; a6+=q1.z; a7+=q1.w;
    float inv = sm->a1.sinv[g][h];
    a0*=inv; a1*=inv; a2*=inv; a3*=inv; a4*=inv; a5*=inv; a6*=inv; a7*=inv;
    a0 = a0>0.f ? a0 : __expf(a0)-1.f;   // ELU
    a1 = a1>0.f ? a1 : __expf(a1)-1.f;
    a2 = a2>0.f ? a2 : __expf(a2)-1.f;
    a3 = a3>0.f ? a3 : __expf(a3)-1.f;
    a4 = a4>0.f ? a4 : __expf(a4)-1.f;
    a5 = a5>0.f ? a5 : __expf(a5)-1.f;
    a6 = a6>0.f ? a6 : __expf(a6)-1.f;
    a7 = a7>0.f ? a7 : __expf(a7)-1.f;
    uint4 o4;
    o4.x = (unsigned int)f2bf(a0) | ((unsigned int)f2bf(a1)<<16);
    o4.y = (unsigned int)f2bf(a2) | ((unsigned int)f2bf(a3)<<16);
    o4.z = (unsigned int)f2bf(a4) | ((unsigned int)f2bf(a5)<<16);
    o4.w = (unsigned int)f2bf(a6) | ((unsigned int)f2bf(a7)<<16);
    *(uint4*)(x + (long)n*HID + c0) = o4;
  }
}

// Layer-2 agg for one node, executed by a 64-thread sub-block g (R7 agg2_k body).
__device__ void agg2_node(SMem* sm, int g, int t, int n, const unsigned short* fb,
                          const float* el, const float* er, const int* cnt,
                          const int* bucket, void* out, int md){
  long off = (long)n*CAP;
  int deg = cnt[n]; if(deg>CAP) deg=CAP;
  int* sidx = sm->a2.sidx[g];
  float* wl = sm->a2.wl[g];
  for(int i=t;i<deg;i+=64) sidx[i]=bucket[off+i];
  __syncthreads();
  float ern = er[n];
  float pw = 0.f;
  for(int i=t;i<deg;i+=64){
    int s = sidx[i];
    float e = el[s]+ern; e = e>0.f ? e : NEG*e;
    float w = __expf(e);
    wl[i]=w;
    pw += w;
  }
  #pragma unroll
  for(int o=32;o>0;o>>=1) pw += __shfl_xor(pw,o);
  float inv = pw>0.f ? 1.f/pw : 0.f;
  __syncthreads();
  int half = t>>5, l = t&31;
  int c0 = 8*l;
  float a0=0.f,a1=0.f,a2=0.f,a3=0.f,a4=0.f,a5=0.f,a6=0.f,a7=0.f;
  #pragma unroll 4
  for(int i=half; i<deg; i+=2){
    int s = sidx[i];
    float w = wl[i];
    uint4 u = *(const uint4*)(fb + (long)s*OUT_DIM + c0);
    a0 += w*bflo(u.x); a1 += w*bfhi(u.x);
    a2 += w*bflo(u.y); a3 += w*bfhi(u.y);
    a4 += w*bflo(u.z); a5 += w*bfhi(u.z);
    a6 += w*bflo(u.w); a7 += w*bfhi(u.w);
  }
  a0 += __shfl_xor(a0,32); a1 += __shfl_xor(a1,32);
  a2 += __shfl_xor(a2,32); a3 += __shfl_xor(a3,32);
  a4 += __shfl_xor(a4,32); a5 += __shfl_xor(a5,32);
  a6 += __shfl_xor(a6,32); a7 += __shfl_xor(a7,32);
  if(half==0){
    a0*=inv; a1*=inv; a2*=inv; a3*=inv; a4*=inv; a5*=inv; a6*=inv; a7*=inv;
    long oi = (long)n*OUT_DIM + c0;
    if(md){
      float* of = (float*)out;
      *(float4*)(of+oi)   = make_float4(a0,a1,a2,a3);
      *(float4*)(of+oi+4) = make_float4(a4,a5,a6,a7);
    } else {
      unsigned short* ob = (unsigned short*)out;
      uint4 o4;
      o4.x = (unsigned int)f2bf(a0) | ((unsigned int)f2bf(a1)<<16);
      o4.y = (unsigned int)f2bf(a2) | ((unsigned int)f2bf(a3)<<16);
      o4.z = (unsigned int)f2bf(a4) | ((unsigned int)f2bf(a5)<<16);
      o4.w = (unsigned int)f2bf(a6) | ((unsigned int)f2bf(a7)<<16);
      *(uint4*)(ob+oi) = o4;
    }
  }
}

// ---- single persistent kernel: 5 phases, 4 software grid barriers ----
__global__ __launch_bounds__(256,4) void fused_k(
    const void* h_in, const void* W1, const void* al1, const void* ar1,
    const void* W2, const void* al2, const void* ar2,
    const int* src, const int* dst, int E,
    unsigned short* f1b, unsigned short* f2b, unsigned short* xbuf,
    unsigned short* wt1, unsigned short* wt2,
    float* el1, float* er1, float* el2, float* er2,
    int* cnt, int* bucket, int* modep, int* bar, void* out){
  int blk = blockIdx.x, t = threadIdx.x;
  __shared__ SMem sm;

  // phase 0: transpose (blocks 0..TB-1), global sniff (TB), zero (TB+1..TB+ZB)
  if(blk < TB){
    transpose_tile(&sm, blk, t, W1, W2, wt1, wt2);
  } else if(blk == TB){
    const unsigned short* w1raw = (const unsigned short*)W1;
    if(t==0) sm.sn.sbad=0;
    __syncthreads();
    int bad=0;
    for(int i=t;i<512;i+=256){
      unsigned int u = ((unsigned int)w1raw[i])<<16;
      float f = __uint_as_float(u);
      if(!(f==f) || fabsf(f) > 100.0f) bad++;
    }
    #pragma unroll
    for(int o=32;o>0;o>>=1) bad += __shfl_down(bad,o);
    if((t&63)==0) atomicAdd(&sm.sn.sbad, bad);
    __syncthreads();
    if(t==0) *modep = (sm.sn.sbad>10) ? 1 : 0;
  } else if(blk < TB+1+ZB){
    int i = (blk-TB-1)*256 + t;
    if(i<N_NODES){ cnt[i]=0; el2[i]=0.f; er2[i]=0.f; }
  }
  gridbar(bar, 0);
  int md = *modep;

  // phase B: gemm1 tiles on blocks [0,GB1); edge-bucket scatter on the rest
  if(blk < GB1){
    gemm_tile(&sm, h_in, wt1, f1b, N_NODES, HID, IN_DIM, md, md,
              al1, ar1, el1, er1, 1, blk, HID/128, t);
  } else {
    for(long e=(long)(blk-GB1)*256 + t; e<E; e+=(long)(GRID-GB1)*256){
      int d = dst[e];
      int pos = atomicAdd(&cnt[d], 1);
      if(pos < CAP) bucket[(long)d*CAP + pos] = src[e];
    }
  }
  gridbar(bar, 1);

  // phase C: layer-1 aggregation + ELU, 2 nodes per block per iteration
  {
    int g = t>>7, t128 = t&127;
    for(int i=blk; i<N_NODES/2; i+=GRID){
      int n = i*2 + g;
      agg1_node(&sm, g, t128, n, f1b, el1, er1, cnt, bucket, xbuf);
      __syncthreads();
    }
  }
  gridbar(bar, 2);

  // phase D: gemm2 tiles on blocks [0,GB2)
  if(blk < GB2){
    gemm_tile(&sm, xbuf, wt2, f2b, N_NODES, OUT_DIM, HID, 0, md,
              al2, ar2, el2, er2, 2, blk, OUT_DIM/128, t);
  }
  gridbar(bar, 3);

  // phase E: layer-2 aggregation, 4 nodes per block per iteration
  {
    int g = t>>6, t64 = t&63;
    for(int i=blk; i<N_NODES/4; i+=GRID){
      int n = i*4 + g;
      agg2_node(&sm, g, t64, n, f2b, el2, er2, cnt, bucket, out, md);
      __syncthreads();
    }
  }
}

extern "C" void kernel_launch(void* const* d_in, const int* in_sizes, int n_in,
                              void* d_out, int out_size, void* d_ws, size_t ws_size,
                              hipStream_t stream){
  (void)n_in; (void)out_size; (void)ws_size;
  const void* h_in = d_in[0];
  const void* W1   = d_in[1];
  const void* al1  = d_in[2];
  const void* ar1  = d_in[3];
  const void* W2   = d_in[4];
  const void* al2  = d_in[5];
  const void* ar2  = d_in[6];
  const int* src = (const int*)d_in[7];
  const int* dst = (const int*)d_in[8];
  int E = in_sizes[7];

  char* ws = (char*)d_ws;
  size_t o = 0;
  auto alloc = [&](size_t b){ size_t c=o; o += (b+255)&~(size_t)255; return c; };
  unsigned short* f1b  = (unsigned short*)(ws + alloc((size_t)N_NODES*HID*2));
  unsigned short* f2b  = (unsigned short*)(ws + alloc((size_t)N_NODES*OUT_DIM*2));
  unsigned short* xbuf = (unsigned short*)(ws + alloc((size_t)N_NODES*HID*2));
  unsigned short* wt1  = (unsigned short*)(ws + alloc((size_t)IN_DIM*HID*2));
  unsigned short* wt2  = (unsigned short*)(ws + alloc((size_t)HID*OUT_DIM*2));
  float* el1   = (float*)(ws + alloc((size_t)N_NODES*HEADS*4));
  float* er1   = (float*)(ws + alloc((size_t)N_NODES*HEADS*4));
  float* el2   = (float*)(ws + alloc((size_t)N_NODES*4));
  float* er2   = (float*)(ws + alloc((size_t)N_NODES*4));
  int* cnt     = (int*)(ws + alloc((size_t)N_NODES*4));
  int* bucket  = (int*)(ws + alloc((size_t)N_NODES*CAP*4));
  int* modep   = (int*)(ws + alloc(256));
  int* bar     = (int*)(ws + alloc(1024));   // 4 barriers x 64 ints (counter+flag on separate 128B lines)

  // zero the 4 barrier counters+flags (capturable async memset, per-invocation)
  hipMemsetAsync(bar, 0, 1024, stream);

  fused_k<<<GRID,256,0,stream>>>(
      h_in, W1, al1, ar1, W2, al2, ar2, src, dst, E,
      f1b, f2b, xbuf, wt1, wt2, el1, er1, el2, er2,
      cnt, bucket, modep, bar, d_out);
}

// Round 19
// 173.592 us; speedup vs baseline: 5.8225x; 5.7023x over previous
//
#include <hip/hip_runtime.h>
#include <hip/hip_bf16.h>

#define N_NODES 10000
#define IN_DIM 256
#define HID 512      // HEADS*HIDDEN
#define HEADS 8
#define OUT_DIM 256
#define NEG 0.2f
#define CAP 128      // bucket capacity per node (actual max deg ~57 incl self-loop)
#define ZB 40        // zero blocks: ceil(10000/256)
#define TB 64        // transpose blocks: 32 (W1) + 32 (W2)

typedef __hip_bfloat16 bf16;
typedef __attribute__((ext_vector_type(8))) short short8;
typedef __attribute__((ext_vector_type(4))) float f32x4;

__device__ __forceinline__ float ldm(const void* p, long i, int mode){
  if(mode) return ((const float*)p)[i];
  return __bfloat162float(((const bf16*)p)[i]);
}
__device__ __forceinline__ unsigned short f2bf(float f){
  bf16 b = __float2bfloat16(f);
  return *(unsigned short*)&b;
}
__device__ __forceinline__ float bflo(unsigned int u){ return __uint_as_float(u<<16); }
__device__ __forceinline__ float bfhi(unsigned int u){ return __uint_as_float(u&0xffff0000u); }

// One prep kernel: block 0 = mode sniff (for gemm/agg2); blocks [1,1+ZB) zero
// cnt/el2/er2; blocks [1+ZB, 1+ZB+TB) = 64x64 LDS-tiled weight transpose with
// LOCAL mode sniff (no cross-block dependency on modep).
__global__ void prep_all_k(const unsigned short* w1raw, const void* W1, const void* W2,
                           unsigned short* wt1, unsigned short* wt2, int* modep,
                           int* cnt, float* el2, float* er2){
  int b = blockIdx.x, t = threadIdx.x;
  if(b==0){
    __shared__ int sbad;
    if(t==0) sbad=0;
    __syncthreads();
    int bad=0;
    for(int i=t;i<512;i+=256){
      unsigned int u = ((unsigned int)w1raw[i])<<16;
      float f = __uint_as_float(u);
      if(!(f==f) || fabsf(f) > 100.0f) bad++;
    }
    #pragma unroll
    for(int o=32;o>0;o>>=1) bad += __shfl_down(bad,o);
    if((t&63)==0) atomicAdd(&sbad, bad);
    __syncthreads();
    if(t==0) *modep = (sbad>10) ? 1 : 0;
    return;
  }
  if(b < 1+ZB){
    int i = (b-1)*256 + t;
    if(i<N_NODES){ cnt[i]=0; el2[i]=0.f; er2[i]=0.f; }
    return;
  }
  // transpose blocks: self-sniff mode (same rule as block 0)
  __shared__ int sbad;
  __shared__ __align__(16) unsigned short tl[64*72];   // pad 72 to spread banks
  if(t==0) sbad=0;
  __syncthreads();
  int bad=0;
  for(int i=t;i<512;i+=256){
    unsigned int u = ((unsigned int)w1raw[i])<<16;
    float f = __uint_as_float(u);
    if(!(f==f) || fabsf(f) > 100.0f) bad++;
  }
  #pragma unroll
  for(int o=32;o>0;o>>=1) bad += __shfl_down(bad,o);
  if((t&63)==0) atomicAdd(&sbad, bad);
  __syncthreads();
  int md = sbad>10;
  int bb0 = b - (1+ZB);
  int isW2 = (bb0>=32);
  int bb = isW2 ? bb0-32 : bb0;
  const void* W = isW2 ? W2 : W1;
  unsigned short* wt = isW2 ? wt2 : wt1;
  int K = isW2 ? HID : IN_DIM;      // rows of W (contraction dim)
  int N = isW2 ? OUT_DIM : HID;     // cols of W
  int sh = isW2 ? 2 : 3;            // log2(ntiles in N)
  int kt = bb >> sh, nt = bb & ((1<<sh)-1);
  int r = t>>2, c0 = (t&3)<<4;      // each thread: 16 elems of one row
  long srow = (long)(kt*64 + r)*N + nt*64 + c0;
  unsigned short v[16] __attribute__((aligned(16)));
  if(md){
    const float* Wf = (const float*)W;
    #pragma unroll
    for(int j=0;j<16;j+=4){
      float4 xv = *(const float4*)(Wf + srow + j);
      v[j]=f2bf(xv.x); v[j+1]=f2bf(xv.y); v[j+2]=f2bf(xv.z); v[j+3]=f2bf(xv.w);
    }
  } else {
    const unsigned short* Wb = (const unsigned short*)W;
    *(short8*)&v[0] = *(const short8*)(Wb+srow);
    *(short8*)&v[8] = *(const short8*)(Wb+srow+8);
  }
  #pragma unroll
  for(int j=0;j<16;j++) tl[(c0+j)*72 + r] = v[j];     // transposed LDS write
  __syncthreads();
  int nn = t>>2, k0 = (t&3)<<4;
  short8 o0 = *(short8*)&tl[nn*72+k0];                // contiguous LDS read
  short8 o1 = *(short8*)&tl[nn*72+k0+8];
  long drow = (long)(nt*64+nn)*K + kt*64 + k0;
  *(short8*)(wt+drow)   = o0;                         // coalesced 16B stores
  *(short8*)(wt+drow+8) = o1;
}

// C[M,N]bf16 = A[M,K] @ Bt[N,K]^T with fused attention-dot epilogue.
// BM=64 x BN=128 tile, BK=64, register double-buffer prefetch.
// 4 waves: wave w -> rows (w>>1)*32, cols (w&1)*64; acc[2][4] 16x16 frags;
// 16 MFMA per K-step between each barrier pair (2x the old BN=64 tile).
// Halves A re-reads: col-tiles 8->4 (gemm1) / 4->2 (gemm2).
// Blocks >= gemmBlocks instead run the edge-bucket scatter (independent work
// hidden under the gemm; pass E=0 to disable).
// dmode==1: el/er direct-STORE; tile spans 2 heads (head = 2*bx + colhalf).
// dmode==2: el/er atomicAdd (stride 1, col-tiles contribute).
__global__ __launch_bounds__(256) void gemm_k(const void* A, const unsigned short* Bt,
                                              unsigned short* C, int M, int N, int K,
                                              int asel, const int* modep,
                                              const void* al, const void* ar,
                                              float* el, float* er, int dmode,
                                              const int* src, const int* dst,
                                              int* cnt, int* bucket, int E,
                                              int gemmBlocks, int nbx){
  int blk = blockIdx.x;
  if(blk >= gemmBlocks){
    int e = (blk-gemmBlocks)*256 + threadIdx.x;
    if(e<E){
      int d = dst[e];
      int pos = atomicAdd(&cnt[d], 1);
      if(pos < CAP) bucket[(long)d*CAP + pos] = src[e];
    }
    return;
  }
  int md = *modep;
  int am = asel ? md : 0;   // 1 -> A is f32
  __shared__ short As[64*72];
  __shared__ short Bs[128*72];
  __shared__ float led[64][2], ler[64][2];
  int t = threadIdx.x;
  int lane = t & 63, wave = t >> 6;
  int l15 = lane & 15, quad = lane >> 4;
  int wm = (wave>>1)*32, wn = (wave&1)*64;
  int bx = blk % nbx, by = blk / nbx;
  int mbase = by*64, nbase = bx*128;

  f32x4 acc[2][4];
  #pragma unroll
  for(int i=0;i<2;i++)
    #pragma unroll
    for(int j=0;j<4;j++) acc[i][j] = (f32x4){0.f,0.f,0.f,0.f};

  // A: row = t>>2 (64 rows), 16 K-elems at (t&3)*16
  // B: row = t>>1 (128 rows), 32 K-elems at (t&1)*32
  int arw = t>>2, akk = (t&3)*16;
  int brw = t>>1, bkk = (t&1)*32;
  long arow = (long)(mbase+arw)*K, brow = (long)(nbase+brw)*K;
  bool av = (mbase+arw) < M;
  const unsigned short* Ab = (const unsigned short*)A;
  const float* Af = (const float*)A;

  short8 a0,a1,b0,b1,b2,b3, na0,na1,nb0,nb1,nb2,nb3;
  a0=a1 = (short8){0,0,0,0,0,0,0,0};
  na0=na1 = (short8){0,0,0,0,0,0,0,0};

  // prologue: load tile 0 into regs
  {
    long ao = arow + akk;
    if(am){
      if(av){
        float4 x0 = *(const float4*)(Af+ao),   x1 = *(const float4*)(Af+ao+4);
        float4 x2 = *(const float4*)(Af+ao+8), x3 = *(const float4*)(Af+ao+12);
        a0[0]=f2bf(x0.x);a0[1]=f2bf(x0.y);a0[2]=f2bf(x0.z);a0[3]=f2bf(x0.w);
        a0[4]=f2bf(x1.x);a0[5]=f2bf(x1.y);a0[6]=f2bf(x1.z);a0[7]=f2bf(x1.w);
        a1[0]=f2bf(x2.x);a1[1]=f2bf(x2.y);a1[2]=f2bf(x2.z);a1[3]=f2bf(x2.w);
        a1[4]=f2bf(x3.x);a1[5]=f2bf(x3.y);a1[6]=f2bf(x3.z);a1[7]=f2bf(x3.w);
      }
    } else if(av){
      a0 = *(const short8*)(Ab+ao); a1 = *(const short8*)(Ab+ao+8);
    }
    long bo = brow + bkk;
    b0 = *(const short8*)(Bt+bo);    b1 = *(const short8*)(Bt+bo+8);
    b2 = *(const short8*)(Bt+bo+16); b3 = *(const short8*)(Bt+bo+24);
  }

  for(int k0=0;k0<K;k0+=64){
    // issue next tile's loads early (latency hides under this tile's compute)
    if(k0+64 < K){
      long ao = arow + k0 + 64 + akk;
      if(am){
        if(av){
          float4 x0 = *(const float4*)(Af+ao),   x1 = *(const float4*)(Af+ao+4);
          float4 x2 = *(const float4*)(Af+ao+8), x3 = *(const float4*)(Af+ao+12);
          na0[0]=f2bf(x0.x);na0[1]=f2bf(x0.y);na0[2]=f2bf(x0.z);na0[3]=f2bf(x0.w);
          na0[4]=f2bf(x1.x);na0[5]=f2bf(x1.y);na0[6]=f2bf(x1.z);na0[7]=f2bf(x1.w);
          na1[0]=f2bf(x2.x);na1[1]=f2bf(x2.y);na1[2]=f2bf(x2.z);na1[3]=f2bf(x2.w);
          na1[4]=f2bf(x3.x);na1[5]=f2bf(x3.y);na1[6]=f2bf(x3.z);na1[7]=f2bf(x3.w);
        }
      } else if(av){
        na0 = *(const short8*)(Ab+ao); na1 = *(const short8*)(Ab+ao+8);
      }
      long bo = brow + k0 + 64 + bkk;
      nb0 = *(const short8*)(Bt+bo);    nb1 = *(const short8*)(Bt+bo+8);
      nb2 = *(const short8*)(Bt+bo+16); nb3 = *(const short8*)(Bt+bo+24);
    }
    __syncthreads();                 // previous tile's LDS readers done
    *(short8*)(As + arw*72 + akk)   = a0;
    *(short8*)(As + arw*72 + akk+8) = a1;
    *(short8*)(Bs + brw*72 + bkk)    = b0;
    *(short8*)(Bs + brw*72 + bkk+8)  = b1;
    *(short8*)(Bs + brw*72 + bkk+16) = b2;
    *(short8*)(Bs + brw*72 + bkk+24) = b3;
    __syncthreads();
    #pragma unroll
    for(int ks=0;ks<2;ks++){
      short8 af[2], bfr[4];
      #pragma unroll
      for(int mi=0;mi<2;mi++) af[mi]  = *(short8*)(As + (wm + mi*16 + l15)*72 + ks*32 + quad*8);
      #pragma unroll
      for(int ni=0;ni<4;ni++) bfr[ni] = *(short8*)(Bs + (wn + ni*16 + l15)*72 + ks*32 + quad*8);
      #pragma unroll
      for(int mi=0;mi<2;mi++)
        #pragma unroll
        for(int ni=0;ni<4;ni++)
          acc[mi][ni] = __builtin_amdgcn_mfma_f32_16x16x32_bf16(af[mi], bfr[ni], acc[mi][ni], 0,0,0);
    }
    a0=na0; a1=na1; b0=nb0; b1=nb1; b2=nb2; b3=nb3;
  }

  // C store (bf16)
  #pragma unroll
  for(int mi=0;mi<2;mi++){
    #pragma unroll
    for(int ni=0;ni<4;ni++){
      int grow0 = mbase + wm + mi*16 + quad*4;
      int gcol  = nbase + wn + ni*16 + l15;
      #pragma unroll
      for(int r=0;r<4;r++){
        int grow = grow0 + r;
        if(grow < M) C[(long)grow*N + gcol] = f2bf(acc[mi][ni][r]);
      }
    }
  }

  // fused dots epilogue: partial el/er for this block's 64 rows.
  // This wave's 64 cols belong to ONE head-half: hh = wn>>6 (0 or 1).
  float avv[4], rvv[4];
  #pragma unroll
  for(int ni=0;ni<4;ni++){
    int gc = nbase + wn + ni*16 + l15;
    avv[ni] = ldm(al, gc, md);
    rvv[ni] = ldm(ar, gc, md);
  }
  int hh = wn>>6;
  __syncthreads();
  if(t<128){ led[t&63][t>>6]=0.f; ler[t&63][t>>6]=0.f; }
  __syncthreads();
  #pragma unroll
  for(int mi=0;mi<2;mi++){
    #pragma unroll
    for(int r=0;r<4;r++){
      float pl = acc[mi][0][r]*avv[0] + acc[mi][1][r]*avv[1]
               + acc[mi][2][r]*avv[2] + acc[mi][3][r]*avv[3];
      float pr = acc[mi][0][r]*rvv[0] + acc[mi][1][r]*rvv[1]
               + acc[mi][2][r]*rvv[2] + acc[mi][3][r]*rvv[3];
      #pragma unroll
      for(int o=1;o<16;o<<=1){ pl += __shfl_xor(pl,o); pr += __shfl_xor(pr,o); }
      if(l15==0){
        int lr = wm + mi*16 + quad*4 + r;
        atomicAdd(&led[lr][hh], pl);
        atomicAdd(&ler[lr][hh], pr);
      }
    }
  }
  __syncthreads();
  if(dmode==1){
    if(t<128){
      int grow = mbase + (t&63);
      int h2 = t>>6;
      if(grow < M){
        el[(long)grow*HEADS + 2*bx + h2] = led[t&63][h2];
        er[(long)grow*HEADS + 2*bx + h2] = ler[t&63][h2];
      }
    }
  } else {
    if(t<64){
      int grow = mbase + t;
      if(grow < M){
        atomicAdd(&el[grow], led[t][0]+led[t][1]);
        atomicAdd(&er[grow], ler[t][0]+ler[t][1]);
      }
    }
  }
}

// Layer-1 agg, merged: grid = N_NODES, 128 threads (2 waves).
// Weight phase: 128 threads edge-parallel, all 8 heads per edge.
// Agg phase: wave w handles neighbors i ≡ w (mod 2); lane l owns cols 8l..8l+7
// (head l>>3) with uint4 (16B) gathers — full 512-col row per wave-neighbor.
__global__ __launch_bounds__(128) void agg1_k(const unsigned short* fb, const float* el,
                       const float* er, const int* cnt, const int* bucket, unsigned short* x){
  int n = blockIdx.x;
  int t = threadIdx.x;
  long off = (long)n*CAP;
  int deg = cnt[n]; if(deg>CAP) deg=CAP;
  __shared__ int sidx[CAP];
  __shared__ __align__(16) float swl[CAP*8];   // [edge][head]
  __shared__ float pws[2][8];
  __shared__ float sinv[8];
  __shared__ __align__(16) float pacc[64][8];
  for(int i=t;i<deg;i+=128) sidx[i]=bucket[off+i];
  __syncthreads();
  const float* erp = er + (long)n*HEADS;
  float4 era = *(const float4*)erp, erb = *(const float4*)(erp+4);
  float err8[8] = {era.x,era.y,era.z,era.w,erb.x,erb.y,erb.z,erb.w};
  float pw[8];
  #pragma unroll
  for(int j=0;j<8;j++) pw[j]=0.f;
  for(int i=t;i<deg;i+=128){
    int s = sidx[i];
    const float* ep = el + (long)s*HEADS;
    float4 ea = *(const float4*)ep, eb = *(const float4*)(ep+4);
    float ev[8] = {ea.x,ea.y,ea.z,ea.w,eb.x,eb.y,eb.z,eb.w};
    float wv[8];
    #pragma unroll
    for(int j=0;j<8;j++){
      float e = ev[j] + err8[j];
      e = e>0.f ? e : NEG*e;
      float w = __expf(e);
      wv[j]=w; pw[j]+=w;
    }
    *(float4*)&swl[i*8]   = make_float4(wv[0],wv[1],wv[2],wv[3]);
    *(float4*)&swl[i*8+4] = make_float4(wv[4],wv[5],wv[6],wv[7]);
  }
  #pragma unroll
  for(int o=32;o>0;o>>=1)
    #pragma unroll
    for(int j=0;j<8;j++) pw[j]+=__shfl_xor(pw[j],o);
  int wv_ = t>>6, l = t&63;
  if(l==0){
    #pragma unroll
    for(int j=0;j<8;j++) pws[wv_][j]=pw[j];
  }
  __syncthreads();
  if(t<8){ float s2 = pws[0][t]+pws[1][t]; sinv[t] = s2>0.f ? 1.f/s2 : 0.f; }
  __syncthreads();
  int h = l>>3;
  int c0 = 8*l;
  float a0=0.f,a1=0.f,a2=0.f,a3=0.f,a4=0.f,a5=0.f,a6=0.f,a7=0.f;
  #pragma unroll 4
  for(int i=wv_; i<deg; i+=2){
    int s = sidx[i];
    float w = swl[i*8+h];
    uint4 u = *(const uint4*)(fb + (long)s*HID + c0);
    a0 += w*bflo(u.x); a1 += w*bfhi(u.x);
    a2 += w*bflo(u.y); a3 += w*bfhi(u.y);
    a4 += w*bflo(u.z); a5 += w*bfhi(u.z);
    a6 += w*bflo(u.w); a7 += w*bfhi(u.w);
  }
  if(wv_==1){
    *(float4*)&pacc[l][0] = make_float4(a0,a1,a2,a3);
    *(float4*)&pacc[l][4] = make_float4(a4,a5,a6,a7);
  }
  __syncthreads();
  if(wv_==0){
    float4 q0 = *(float4*)&pacc[l][0], q1 = *(float4*)&pacc[l][4];
    a0+=q0.x; a1+=q0.y; a2+=q0.z; a3+=q0.w;
    a4+=q1.x; a5+=q1.y; a6+=q1.z; a7+=q1.w;
    float inv = sinv[h];
    a0*=inv; a1*=inv; a2*=inv; a3*=inv; a4*=inv; a5*=inv; a6*=inv; a7*=inv;
    a0 = a0>0.f ? a0 : __expf(a0)-1.f;   // ELU
    a1 = a1>0.f ? a1 : __expf(a1)-1.f;
    a2 = a2>0.f ? a2 : __expf(a2)-1.f;
    a3 = a3>0.f ? a3 : __expf(a3)-1.f;
    a4 = a4>0.f ? a4 : __expf(a4)-1.f;
    a5 = a5>0.f ? a5 : __expf(a5)-1.f;
    a6 = a6>0.f ? a6 : __expf(a6)-1.f;
    a7 = a7>0.f ? a7 : __expf(a7)-1.f;
    uint4 o4;
    o4.x = (unsigned int)f2bf(a0) | ((unsigned int)f2bf(a1)<<16);
    o4.y = (unsigned int)f2bf(a2) | ((unsigned int)f2bf(a3)<<16);
    o4.z = (unsigned int)f2bf(a4) | ((unsigned int)f2bf(a5)<<16);
    o4.w = (unsigned int)f2bf(a6) | ((unsigned int)f2bf(a7)<<16);
    *(uint4*)(x + (long)n*HID + c0) = o4;
  }
}

// Layer-2 agg: grid = N_NODES, 1 wave; half-wave h handles neighbors i ≡ h (mod 2),
// lane l (&31) owns cols 8l..8l+7 with uint4 gathers; shfl_xor(32) combines halves.
__global__ __launch_bounds__(64) void agg2_k(const unsigned short* fb, const float* el,
                       const float* er, const int* cnt, const int* bucket, void* out,
                       const int* modep){
  int md = *modep;
  int n = blockIdx.x, t = threadIdx.x;
  long off = (long)n*CAP;
  int deg = cnt[n]; if(deg>CAP) deg=CAP;
  __shared__ int sidx[CAP];
  __shared__ float wl[CAP];
  for(int i=t;i<deg;i+=64) sidx[i]=bucket[off+i];
  __syncthreads();
  float ern = er[n];
  float pw = 0.f;
  for(int i=t;i<deg;i+=64){
    int s = sidx[i];
    float e = el[s]+ern; e = e>0.f ? e : NEG*e;
    float w = __expf(e);
    wl[i]=w;
    pw += w;
  }
  #pragma unroll
  for(int o=32;o>0;o>>=1) pw += __shfl_xor(pw,o);
  float inv = pw>0.f ? 1.f/pw : 0.f;
  __syncthreads();
  int half = t>>5, l = t&31;
  int c0 = 8*l;
  float a0=0.f,a1=0.f,a2=0.f,a3=0.f,a4=0.f,a5=0.f,a6=0.f,a7=0.f;
  #pragma unroll 4
  for(int i=half; i<deg; i+=2){
    int s = sidx[i];
    float w = wl[i];
    uint4 u = *(const uint4*)(fb + (long)s*OUT_DIM + c0);
    a0 += w*bflo(u.x); a1 += w*bfhi(u.x);
    a2 += w*bflo(u.y); a3 += w*bfhi(u.y);
    a4 += w*bflo(u.z); a5 += w*bfhi(u.z);
    a6 += w*bflo(u.w); a7 += w*bfhi(u.w);
  }
  a0 += __shfl_xor(a0,32); a1 += __shfl_xor(a1,32);
  a2 += __shfl_xor(a2,32); a3 += __shfl_xor(a3,32);
  a4 += __shfl_xor(a4,32); a5 += __shfl_xor(a5,32);
  a6 += __shfl_xor(a6,32); a7 += __shfl_xor(a7,32);
  if(half==0){
    a0*=inv; a1*=inv; a2*=inv; a3*=inv; a4*=inv; a5*=inv; a6*=inv; a7*=inv;
    long oi = (long)n*OUT_DIM + c0;
    if(md){
      float* of = (float*)out;
      *(float4*)(of+oi)   = make_float4(a0,a1,a2,a3);
      *(float4*)(of+oi+4) = make_float4(a4,a5,a6,a7);
    } else {
      unsigned short* ob = (unsigned short*)out;
      uint4 o4;
      o4.x = (unsigned int)f2bf(a0) | ((unsigned int)f2bf(a1)<<16);
      o4.y = (unsigned int)f2bf(a2) | ((unsigned int)f2bf(a3)<<16);
      o4.z = (unsigned int)f2bf(a4) | ((unsigned int)f2bf(a5)<<16);
      o4.w = (unsigned int)f2bf(a6) | ((unsigned int)f2bf(a7)<<16);
      *(uint4*)(ob+oi) = o4;
    }
  }
}

extern "C" void kernel_launch(void* const* d_in, const int* in_sizes, int n_in,
                              void* d_out, int out_size, void* d_ws, size_t ws_size,
                              hipStream_t stream){
  (void)n_in; (void)out_size; (void)ws_size;
  const void* h_in = d_in[0];
  const void* W1   = d_in[1];
  const void* al1  = d_in[2];
  const void* ar1  = d_in[3];
  const void* W2   = d_in[4];
  const void* al2  = d_in[5];
  const void* ar2  = d_in[6];
  const int* src = (const int*)d_in[7];
  const int* dst = (const int*)d_in[8];
  int E = in_sizes[7];

  char* ws = (char*)d_ws;
  size_t o = 0;
  auto alloc = [&](size_t b){ size_t c=o; o += (b+255)&~(size_t)255; return c; };
  unsigned short* f1b  = (unsigned short*)(ws + alloc((size_t)N_NODES*HID*2));
  unsigned short* f2b  = (unsigned short*)(ws + alloc((size_t)N_NODES*OUT_DIM*2));
  unsigned short* xbuf = (unsigned short*)(ws + alloc((size_t)N_NODES*HID*2));
  unsigned short* wt1  = (unsigned short*)(ws + alloc((size_t)IN_DIM*HID*2));
  unsigned short* wt2  = (unsigned short*)(ws + alloc((size_t)HID*OUT_DIM*2));
  float* el1   = (float*)(ws + alloc((size_t)N_NODES*HEADS*4));
  float* er1   = (float*)(ws + alloc((size_t)N_NODES*HEADS*4));
  float* el2   = (float*)(ws + alloc((size_t)N_NODES*4));
  float* er2   = (float*)(ws + alloc((size_t)N_NODES*4));
  int* cnt     = (int*)(ws + alloc((size_t)N_NODES*4));
  int* bucket  = (int*)(ws + alloc((size_t)N_NODES*CAP*4));
  int* modep   = (int*)(ws + alloc(256));

  // 1) mode sniff + zero cnt/el2/er2 + weight transpose (self-sniffed)
  prep_all_k<<<1+ZB+TB,256,0,stream>>>(
      (const unsigned short*)W1, W1, W2, wt1, wt2, modep, cnt, el2, er2);

  // 2) layer-1 gemm (+fused dots1, direct store) with edge-bucket scatter
  //    hidden in trailing blocks (scatter independent of wt1/gemm output)
  int gb1 = (HID/128)*((N_NODES+63)/64);
  int sb  = (E+255)/256;
  gemm_k<<<gb1+sb,256,0,stream>>>(
      h_in, wt1, f1b, N_NODES, HID, IN_DIM, 1, modep, al1, ar1, el1, er1, 1,
      src, dst, cnt, bucket, E, gb1, HID/128);

  // 3) layer-1 aggregation + ELU
  agg1_k<<<N_NODES,128,0,stream>>>(f1b, el1, er1, cnt, bucket, xbuf);

  // 4) layer-2 gemm (+fused dots2, atomic), no scatter blocks
  int gb2 = (OUT_DIM/128)*((N_NODES+63)/64);
  gemm_k<<<gb2,256,0,stream>>>(
      xbuf, wt2, f2b, N_NODES, OUT_DIM, HID, 0, modep, al2, ar2, el2, er2, 2,
      src, dst, cnt, bucket, 0, gb2, OUT_DIM/128);

  // 5) layer-2 aggregation
  agg2_k<<<N_NODES,64,0,stream>>>(f2b, el2, er2, cnt, bucket, d_out, modep);
}